// Round 8
// baseline (135.487 us; speedup 1.0000x reference)
//
#include <hip/hip_runtime.h>
#include <hip/hip_bf16.h>

#define TOK_S    4096
#define NBI      1089      // 33*33
#define NBI_P    1092
#define KP_BI    1120      // A-matrix K padded to multiple of 32
#define NTRI     512
#define NHID     256
#define NROWS    4096
#define HSTRIDE  260       // sH pad

#define HBLKS    1024      // hist blocks: 4 rows each
#define TBLKS    204       // transpose blocks: 2048 elems each (204*2048 = 417792 exact)
#define GBLKS    256       // gemm blocks: 128 bi-tiles + 128 tri-tiles (BM=32)
#define NTILES   128       // 32-row tiles
#define TRANS_ELEMS (NHID * KP_BI + NHID * NTRI)   // 417792

typedef __attribute__((ext_vector_type(8))) short short8;   // 8 bf16
typedef __attribute__((ext_vector_type(4))) float f32x4;

static __device__ __forceinline__ unsigned int f2bf(float f) {
    __hip_bfloat16 h = __float2bfloat16(f);
    return (unsigned int)*reinterpret_cast<unsigned short*>(&h);
}

union MegaLds {
    struct {
        int   bi [4][1100];   // 17600 B (stride 1100, int4-safe)
        int   tri[4][548];    //  8768 B (512 bins + 32 dump + pad)
        float ps [4][2][2];
    } h;
    float sH[32][HSTRIDE];    // 33280 B (gemm blocks)
};

// ---- proven R6 GEMM+layer2 body (BM=32, N=256, A/B direct from global) ----
template<int KP>
__device__ __forceinline__
void head_body(const __hip_bfloat16* __restrict__ A,
               const __hip_bfloat16* __restrict__ WT,
               const float* __restrict__ b1,
               const float* __restrict__ W2,
               const float* __restrict__ b2,
               const float* __restrict__ inv, const int invoff, const int headoff,
               float* __restrict__ out, const int m0,
               float (*sH)[HSTRIDE])
{
    const int wave = threadIdx.x >> 6;       // 8 waves
    const int lane = threadIdx.x & 63;
    const int wn   = wave * 32;
    const int fr   = lane & 15;
    const int kg   = lane >> 4;

    const __hip_bfloat16* A0 = A  + (size_t)(m0 + fr) * KP + kg * 8;
    const __hip_bfloat16* A1 = A0 + (size_t)16 * KP;
    const __hip_bfloat16* B0 = WT + (size_t)(wn + fr) * KP + kg * 8;
    const __hip_bfloat16* B1 = B0 + (size_t)16 * KP;

    f32x4 acc00 = {}, acc01 = {}, acc10 = {}, acc11 = {};
    #pragma unroll 4
    for (int k = 0; k < KP; k += 32) {
        short8 a0  = *(const short8*)(A0 + k);
        short8 a1  = *(const short8*)(A1 + k);
        short8 b0  = *(const short8*)(B0 + k);
        short8 b1v = *(const short8*)(B1 + k);
        acc00 = __builtin_amdgcn_mfma_f32_16x16x32_bf16(a0, b0,  acc00, 0, 0, 0);
        acc01 = __builtin_amdgcn_mfma_f32_16x16x32_bf16(a0, b1v, acc01, 0, 0, 0);
        acc10 = __builtin_amdgcn_mfma_f32_16x16x32_bf16(a1, b0,  acc10, 0, 0, 0);
        acc11 = __builtin_amdgcn_mfma_f32_16x16x32_bf16(a1, b1v, acc11, 0, 0, 0);
    }

    // D layout: col = lane&15, row = (lane>>4)*4 + reg
    f32x4 accs[2][2] = { {acc00, acc01}, {acc10, acc11} };
    #pragma unroll
    for (int mf = 0; mf < 2; ++mf) {
        #pragma unroll
        for (int nf = 0; nf < 2; ++nf) {
            const int col = wn + nf * 16 + fr;
            const float bias = b1[col];
            #pragma unroll
            for (int r = 0; r < 4; ++r) {
                const int rl = mf * 16 + kg * 4 + r;
                const float iv = inv[(m0 + rl) * 2 + invoff];
                sH[rl][col] = fmaxf(fmaf(accs[mf][nf][r], iv, bias), 0.0f);
            }
        }
    }
    __syncthreads();

    const int r  = threadIdx.x >> 4;
    const int oo = threadIdx.x & 15;
    const float* hr = sH[r];
    float a0 = b2[oo], a1 = b2[oo + 16];
    #pragma unroll 8
    for (int j = 0; j < NHID; j += 4) {
        float4 h = *(const float4*)(hr + j);
        a0 = fmaf(h.x, W2[(j + 0) * 32 + oo], a0);
        a0 = fmaf(h.y, W2[(j + 1) * 32 + oo], a0);
        a0 = fmaf(h.z, W2[(j + 2) * 32 + oo], a0);
        a0 = fmaf(h.w, W2[(j + 3) * 32 + oo], a0);
        a1 = fmaf(h.x, W2[(j + 0) * 32 + oo + 16], a1);
        a1 = fmaf(h.y, W2[(j + 1) * 32 + oo + 16], a1);
        a1 = fmaf(h.z, W2[(j + 2) * 32 + oo + 16], a1);
        a1 = fmaf(h.w, W2[(j + 3) * 32 + oo + 16], a1);
    }
    const size_t ro = (size_t)(m0 + r) * 64 + headoff;
    out[ro + oo]      = a0;
    out[ro + oo + 16] = a1;
}

// ================= single mega launch: hist | transpose | gemm =================
__global__ __launch_bounds__(512, 4)
void ngram_mega(const int* __restrict__ src,
                const float* __restrict__ Wb1, const float* __restrict__ Wt1,
                const float* __restrict__ bb1, const float* __restrict__ Wb2,
                const float* __restrict__ bb2, const float* __restrict__ bt1,
                const float* __restrict__ Wt2, const float* __restrict__ bt2,
                __hip_bfloat16* __restrict__ Abi, __hip_bfloat16* __restrict__ Atri,
                __hip_bfloat16* __restrict__ WbT, __hip_bfloat16* __restrict__ WtT,
                float* __restrict__ inv, int* __restrict__ flags,
                float* __restrict__ out)
{
    __shared__ __align__(16) MegaLds u;
    const int bid = blockIdx.x;
    const int tid = threadIdx.x;

    // ================= role 2: transpose (204 blocks) =================
    if (bid >= HBLKS && bid < HBLKS + TBLKS) {
        int base = (bid - HBLKS) * 2048 + tid;
        const int nb = NHID * KP_BI;
        #pragma unroll
        for (int i = 0; i < 4; ++i) {
            int idx = base + i * 512;
            if (idx < nb) {
                int c = idx / KP_BI, k = idx - c * KP_BI;
                WbT[idx] = __float2bfloat16(k < NBI ? Wb1[k * NHID + c] : 0.0f);
            } else {
                int j = idx - nb;                // < NHID*NTRI (exact tiling)
                int c = j >> 9, k = j & 511;
                WtT[j] = __float2bfloat16(Wt1[k * NHID + c]);
            }
        }
        __syncthreads();                          // drains stores (vmcnt 0)
        if (tid == 0) { __threadfence(); atomicAdd(&flags[NTILES], 1); }
        return;
    }

    // ================= role 3: gemm consumer (256 blocks) =================
    if (bid >= HBLKS + TBLKS) {
        const int g    = bid - (HBLKS + TBLKS);
        const int head = g >> 7;                  // 0 = bi, 1 = tri
        const int mt   = g & 127;                 // 32-row tile
        if (tid == 0) {
            while (__hip_atomic_load(&flags[NTILES], __ATOMIC_RELAXED, __HIP_MEMORY_SCOPE_AGENT) < TBLKS ||
                   __hip_atomic_load(&flags[mt],     __ATOMIC_RELAXED, __HIP_MEMORY_SCOPE_AGENT) < 8) {
                __builtin_amdgcn_s_sleep(8);
            }
            __threadfence();                      // acquire: invalidate stale lines
        }
        __syncthreads();
        if (head == 0)
            head_body<KP_BI>(Abi,  WbT, bb1, Wb2, bb2, inv, 0, 0,  out, mt * 32, u.sH);
        else
            head_body<NTRI>(Atri, WtT, bt1, Wt2, bt2, inv, 1, 32, out, mt * 32, u.sH);
        return;
    }

    // ================= role 1: histograms (1024 blocks, 4 rows each) =================
    const int wave = tid >> 6;
    const int lane = tid & 63;
    const int wrow = wave >> 1;          // row within block (0..3)
    const int wpar = wave & 1;           // half of the row
    const size_t row = (size_t)bid * 4 + wrow;
    const int dump = NTRI + (lane & 31); // trigram dump slots 512..543 (stride 548)

    for (int i = tid; i < 1100; i += 512) ((int4*)u.h.bi)[i]  = int4{0,0,0,0};  // 4400 ints
    for (int i = tid; i < 548;  i += 512) ((int4*)u.h.tri)[i] = int4{0,0,0,0};  // 2192 ints
    __syncthreads();

    int* bi  = u.h.bi[wrow];
    int* tri = u.h.tri[wrow];
    const int4* rowp = (const int4*)(src + row * TOK_S);
    const int*  rowt = src + row * TOK_S;

    // hoisted loads: 4 groups of 8 tokens (+2 overlap) per lane
    int4 A[4], Bv[4];
    int2 E[4];
    #pragma unroll
    for (int jj = 0; jj < 4; ++jj) {
        const int idx = wpar * 256 + jj * 64 + lane;   // [0,512)
        A[jj]  = rowp[2 * idx];
        Bv[jj] = rowp[2 * idx + 1];
        if (idx != 511) E[jj] = *(const int2*)(rowt + 8 * idx + 8);
        else            E[jj] = int2{0, 0};
    }

    #pragma unroll
    for (int jj = 0; jj < 4; ++jj) {
        const int t0 = A[jj].x, t1 = A[jj].y, t2 = A[jj].z, t3 = A[jj].w;
        const int t4 = Bv[jj].x, t5 = Bv[jj].y, t6 = Bv[jj].z, t7 = Bv[jj].w;
        const int t8 = E[jj].x, t9 = E[jj].y;
        const int b0 = t0 * 33 + t1;
        const int b1 = t1 * 33 + t2;
        const int b2 = t2 * 33 + t3;
        const int b3 = t3 * 33 + t4;
        const int b4 = t4 * 33 + t5;
        const int b5 = t5 * 33 + t6;
        const int b6 = t6 * 33 + t7;
        const int b7 = t7 * 33 + t8;
        atomicAdd(&bi[b0], 1);  atomicAdd(&bi[b1], 1);
        atomicAdd(&bi[b2], 1);  atomicAdd(&bi[b3], 1);
        atomicAdd(&bi[b4], 1);  atomicAdd(&bi[b5], 1);
        atomicAdd(&bi[b6], 1);  atomicAdd(&bi[b7], 1);
        const int u0 = (min(min(t0, t1), t2) > 0) ? ((b0 * 33 + t2) & 511) : dump;
        const int u1 = (min(min(t1, t2), t3) > 0) ? ((b1 * 33 + t3) & 511) : dump;
        const int u2 = (min(min(t2, t3), t4) > 0) ? ((b2 * 33 + t4) & 511) : dump;
        const int u3 = (min(min(t3, t4), t5) > 0) ? ((b3 * 33 + t5) & 511) : dump;
        const int u4 = (min(min(t4, t5), t6) > 0) ? ((b4 * 33 + t6) & 511) : dump;
        const int u5 = (min(min(t5, t6), t7) > 0) ? ((b5 * 33 + t7) & 511) : dump;
        const int u6 = (min(min(t6, t7), t8) > 0) ? ((b6 * 33 + t8) & 511) : dump;
        const int u7 = (min(min(t7, t8), t9) > 0) ? ((b7 * 33 + t9) & 511) : dump;
        atomicAdd(&tri[u0], 1); atomicAdd(&tri[u1], 1);
        atomicAdd(&tri[u2], 1); atomicAdd(&tri[u3], 1);
        atomicAdd(&tri[u4], 1); atomicAdd(&tri[u5], 1);
        atomicAdd(&tri[u6], 1); atomicAdd(&tri[u7], 1);
    }
    __syncthreads();

    // export: zero invalid bigram bins; packed bf16 stores; sums for len
    float bsum = 0.0f, tsum = 0.0f;
    __hip_bfloat16* arow = Abi + row * KP_BI;
    for (int g = wpar * 64 + lane; g < KP_BI / 4; g += 128) {   // 280 groups
        uint2 pk{0, 0};
        if (g < NBI_P / 4) {
            int4 v = *(const int4*)&bi[4 * g];
            int b = 4 * g;
            float f0 = (b + 0 >= 33 && (b + 0) % 33 != 0 && b + 0 < NBI) ? (float)v.x : 0.0f;
            float f1 = (b + 1 >= 33 && (b + 1) % 33 != 0 && b + 1 < NBI) ? (float)v.y : 0.0f;
            float f2 = (b + 2 >= 33 && (b + 2) % 33 != 0 && b + 2 < NBI) ? (float)v.z : 0.0f;
            float f3 = (b + 3 >= 33 && (b + 3) % 33 != 0 && b + 3 < NBI) ? (float)v.w : 0.0f;
            bsum += f0 + f1 + f2 + f3;
            pk.x = f2bf(f0) | (f2bf(f1) << 16);
            pk.y = f2bf(f2) | (f2bf(f3) << 16);
        }
        *(uint2*)(arow + 4 * g) = pk;
    }
    {
        const int g = wpar * 64 + lane;    // exactly 128 groups of 4
        int4 v = *(const int4*)&tri[4 * g];
        float f0 = (float)v.x, f1 = (float)v.y, f2 = (float)v.z, f3 = (float)v.w;
        tsum += f0 + f1 + f2 + f3;
        uint2 pk;
        pk.x = f2bf(f0) | (f2bf(f1) << 16);
        pk.y = f2bf(f2) | (f2bf(f3) << 16);
        *(uint2*)(Atri + row * NTRI + 4 * g) = pk;
    }
    #pragma unroll
    for (int s = 32; s; s >>= 1) {
        bsum += __shfl_xor(bsum, s, 64);
        tsum += __shfl_xor(tsum, s, 64);
    }
    if (lane == 0) { u.h.ps[wrow][wpar][0] = bsum; u.h.ps[wrow][wpar][1] = tsum; }
    __syncthreads();
    if (tid < 4) {
        float bs = u.h.ps[tid][0][0] + u.h.ps[tid][1][0];
        float ts = u.h.ps[tid][0][1] + u.h.ps[tid][1][1];
        size_t r2 = ((size_t)bid * 4 + tid) * 2;
        inv[r2 + 0] = 1.0f / fmaxf(bs, 1.0f);
        inv[r2 + 1] = 1.0f / fmaxf(ts, 1.0f);
    }
    __syncthreads();                              // drains inv stores (vmcnt 0)
    if (tid == 0) {
        __threadfence();                          // release: A/inv visible device-wide
        atomicAdd(&flags[bid >> 3], 1);           // tile = 8 hist blocks = 32 rows
    }
}

// ============ launcher ============
extern "C" void kernel_launch(void* const* d_in, const int* in_sizes, int n_in,
                              void* d_out, int out_size, void* d_ws, size_t ws_size,
                              hipStream_t stream) {
    const int*   src = (const int*)  d_in[0];
    const float* Wb1 = (const float*)d_in[1];
    const float* bb1 = (const float*)d_in[2];
    const float* Wb2 = (const float*)d_in[3];
    const float* bb2 = (const float*)d_in[4];
    const float* Wt1 = (const float*)d_in[5];
    const float* bt1 = (const float*)d_in[6];
    const float* Wt2 = (const float*)d_in[7];
    const float* bt2 = (const float*)d_in[8];
    float* outp = (float*)d_out;

    const int B = NROWS;

    char* ws = (char*)d_ws;
    __hip_bfloat16* Abi  = (__hip_bfloat16*)(ws);
    __hip_bfloat16* Atri = (__hip_bfloat16*)(ws + (size_t)B * KP_BI * 2);
    char* ws2 = ws + (size_t)B * KP_BI * 2 + (size_t)B * NTRI * 2;
    __hip_bfloat16* WbT  = (__hip_bfloat16*)(ws2);
    __hip_bfloat16* WtT  = (__hip_bfloat16*)(ws2 + (size_t)NHID * KP_BI * 2);
    char* ws3 = ws2 + (size_t)NHID * KP_BI * 2 + (size_t)NHID * NTRI * 2;
    float* inv   = (float*)(ws3);
    int*   flags = (int*)(ws3 + (size_t)B * 2 * 4);

    // reset producer-consumer flags every call (replay-safe; captured as memset node)
    hipMemsetAsync(flags, 0, (NTILES + 1) * sizeof(int), stream);

    ngram_mega<<<HBLKS + TBLKS + GBLKS, 512, 0, stream>>>(
        src, Wb1, Wt1, bb1, Wb2, bb2, bt1, Wt2, bt2,
        Abi, Atri, WbT, WtT, inv, flags, outp);
}

// Round 9
// 65.818 us; speedup vs baseline: 2.0585x; 2.0585x over previous
//
#include <hip/hip_runtime.h>
#include <hip/hip_bf16.h>

#define TOK_S    4096
#define NBI      1089      // 33*33
#define KP_BI    1120      // A-matrix K padded to multiple of 32
#define NTRI     512
#define NTRI_T   528       // 512 real bins + 16 dump bins
#define NHID     256
#define NROWS    4096
#define HSTRIDE  260       // gemm sH pad

#define HBLKS    256       // hist blocks: 16 rows each, 1 per CU
#define TPB      1632      // transpose elems per hist block (256*1632 = 417792 exact)

typedef __attribute__((ext_vector_type(8))) short short8;   // 8 bf16
typedef __attribute__((ext_vector_type(4))) float f32x4;

// ============ K1: bank-deterministic histograms (16 rows/block) + transpose ============
// Thread t: row r = t&15, segment seg = t>>4 (256 tokens each).
// Tables [bin][8] uint32, rows r and r+8 packed lo/hi 16-bit.
// Atomic bank = ((bin&3)*8 + (r&7)) & 31 -> deterministic <=4-way conflict.
__global__ __launch_bounds__(256)
void hist16(const int* __restrict__ src,
            const float* __restrict__ Wb1, const float* __restrict__ Wt1,
            __hip_bfloat16* __restrict__ Abi,
            __hip_bfloat16* __restrict__ Atri,
            __hip_bfloat16* __restrict__ WbT,
            __hip_bfloat16* __restrict__ WtT,
            float* __restrict__ inv)
{
    __shared__ unsigned int s_bi [NBI * 8];      // 34848 B
    __shared__ unsigned int s_tri[NTRI_T * 8];   // 16896 B
    __shared__ float        s_sum[2][16];

    const int tid = threadIdx.x;
    const int bid = blockIdx.x;
    const int row0 = bid * 16;

    // ---- transpose slice (1632 elems/block, exact tiling) ----
    {
        const int nb = NHID * KP_BI;
        #pragma unroll
        for (int i = 0; i < 7; ++i) {
            int t = tid + i * 256;
            if (t < TPB) {
                int idx = bid * TPB + t;
                if (idx < nb) {
                    int c = idx / KP_BI, k = idx - c * KP_BI;
                    WbT[idx] = __float2bfloat16(k < NBI ? Wb1[k * NHID + c] : 0.0f);
                } else {
                    int j = idx - nb;                 // < NHID*NTRI by construction
                    int c = j >> 9, k = j & 511;
                    WtT[j] = __float2bfloat16(Wt1[k * NHID + c]);
                }
            }
        }
    }

    // ---- zero tables ----
    for (int i = tid; i < (NBI * 8) / 4;    i += 256) ((uint4*)s_bi)[i]  = uint4{0,0,0,0};
    for (int i = tid; i < (NTRI_T * 8) / 4; i += 256) ((uint4*)s_tri)[i] = uint4{0,0,0,0};
    if (tid < 32) s_sum[tid >> 4][tid & 15] = 0.0f;
    __syncthreads();

    const int r    = tid & 15;
    const int seg  = tid >> 4;
    const int col  = r & 7;
    const unsigned int addv = 1u << (16 * (r >> 3));
    const int dumpb = NTRI + seg;                 // distinct dump word per (seg,col)

    const int*  rowt = src + (size_t)(row0 + r) * TOK_S + seg * 256;
    const int4* rowp = (const int4*)rowt;
    int2 ov = (seg != 15) ? *(const int2*)(rowt + 256) : int2{0, 0};

    int4 cur = rowp[0];
    #pragma unroll 8
    for (int g = 0; g < 64; ++g) {
        int4 nxt; int n0, n1;
        if (g < 63) { nxt = rowp[g + 1]; n0 = nxt.x; n1 = nxt.y; }
        else        { nxt = int4{0,0,0,0}; n0 = ov.x; n1 = ov.y; }

        const int b0 = cur.x * 33 + cur.y;
        const int b1 = cur.y * 33 + cur.z;
        const int b2 = cur.z * 33 + cur.w;
        const int b3 = cur.w * 33 + n0;
        atomicAdd(&s_bi[b0 * 8 + col], addv);
        atomicAdd(&s_bi[b1 * 8 + col], addv);
        atomicAdd(&s_bi[b2 * 8 + col], addv);
        atomicAdd(&s_bi[b3 * 8 + col], addv);

        const int u0 = (min(min(cur.x, cur.y), cur.z) > 0) ? ((b0 * 33 + cur.z) & 511) : dumpb;
        const int u1 = (min(min(cur.y, cur.z), cur.w) > 0) ? ((b1 * 33 + cur.w) & 511) : dumpb;
        const int u2 = (min(min(cur.z, cur.w), n0)   > 0) ? ((b2 * 33 + n0)    & 511) : dumpb;
        const int u3 = (min(min(cur.w, n0), n1)      > 0) ? ((b3 * 33 + n1)    & 511) : dumpb;
        atomicAdd(&s_tri[u0 * 8 + col], addv);
        atomicAdd(&s_tri[u1 * 8 + col], addv);
        atomicAdd(&s_tri[u2 * 8 + col], addv);
        atomicAdd(&s_tri[u3 * 8 + col], addv);

        cur = nxt;
    }
    __syncthreads();

    // ---- export: row r, bins seg+16j; zero invalid bigram bins; sums for len ----
    const int shift = 16 * (r >> 3);
    float bsum = 0.0f;
    __hip_bfloat16* arow = Abi + (size_t)(row0 + r) * KP_BI;
    #pragma unroll 4
    for (int j = 0; j < 70; ++j) {
        const int b = seg + 16 * j;               // <= 1119
        float f = 0.0f;
        if (b < NBI) {
            unsigned int c = (s_bi[b * 8 + col] >> shift) & 0xFFFFu;
            int q = b / 33, rem = b - q * 33;     // q = c1, rem = c2
            f = (q > 0 && rem > 0) ? (float)c : 0.0f;
        }
        bsum += f;
        arow[b] = __float2bfloat16(f);
    }
    float tsum = 0.0f;
    __hip_bfloat16* trow = Atri + (size_t)(row0 + r) * NTRI;
    #pragma unroll 4
    for (int j = 0; j < 32; ++j) {
        const int b = seg + 16 * j;
        float f = (float)((s_tri[b * 8 + col] >> shift) & 0xFFFFu);
        tsum += f;
        trow[b] = __float2bfloat16(f);
    }
    atomicAdd(&s_sum[0][r], bsum);
    atomicAdd(&s_sum[1][r], tsum);
    __syncthreads();
    if (tid < 16)
        inv[(size_t)(row0 + tid) * 2 + 0] = 1.0f / fmaxf(s_sum[0][tid], 1.0f);
    else if (tid < 32)
        inv[(size_t)(row0 + tid - 16) * 2 + 1] = 1.0f / fmaxf(s_sum[1][tid - 16], 1.0f);
}

// ============ K2: fused layer1 MFMA GEMM (BM=32, N=256) + relu/len + layer2 ============
template<int KP>
__device__ __forceinline__
void head_body(const __hip_bfloat16* __restrict__ A,
               const __hip_bfloat16* __restrict__ WT,
               const float* __restrict__ b1,
               const float* __restrict__ W2,
               const float* __restrict__ b2,
               const float* __restrict__ inv, const int invoff, const int headoff,
               float* __restrict__ out, const int m0,
               float (*sH)[HSTRIDE])
{
    const int wave = threadIdx.x >> 6;       // 8 waves
    const int lane = threadIdx.x & 63;
    const int wn   = wave * 32;
    const int fr   = lane & 15;
    const int kg   = lane >> 4;

    const __hip_bfloat16* A0 = A  + (size_t)(m0 + fr) * KP + kg * 8;
    const __hip_bfloat16* A1 = A0 + (size_t)16 * KP;
    const __hip_bfloat16* B0 = WT + (size_t)(wn + fr) * KP + kg * 8;
    const __hip_bfloat16* B1 = B0 + (size_t)16 * KP;

    f32x4 acc00 = {}, acc01 = {}, acc10 = {}, acc11 = {};
    #pragma unroll 4
    for (int k = 0; k < KP; k += 32) {
        short8 a0  = *(const short8*)(A0 + k);
        short8 a1  = *(const short8*)(A1 + k);
        short8 b0  = *(const short8*)(B0 + k);
        short8 b1v = *(const short8*)(B1 + k);
        acc00 = __builtin_amdgcn_mfma_f32_16x16x32_bf16(a0, b0,  acc00, 0, 0, 0);
        acc01 = __builtin_amdgcn_mfma_f32_16x16x32_bf16(a0, b1v, acc01, 0, 0, 0);
        acc10 = __builtin_amdgcn_mfma_f32_16x16x32_bf16(a1, b0,  acc10, 0, 0, 0);
        acc11 = __builtin_amdgcn_mfma_f32_16x16x32_bf16(a1, b1v, acc11, 0, 0, 0);
    }

    // D layout: col = lane&15, row = (lane>>4)*4 + reg
    f32x4 accs[2][2] = { {acc00, acc01}, {acc10, acc11} };
    #pragma unroll
    for (int mf = 0; mf < 2; ++mf) {
        #pragma unroll
        for (int nf = 0; nf < 2; ++nf) {
            const int col = wn + nf * 16 + fr;
            const float bias = b1[col];
            #pragma unroll
            for (int q = 0; q < 4; ++q) {
                const int rl = mf * 16 + kg * 4 + q;
                const float iv = inv[(m0 + rl) * 2 + invoff];
                sH[rl][col] = fmaxf(fmaf(accs[mf][nf][q], iv, bias), 0.0f);
            }
        }
    }
    __syncthreads();

    const int rr = threadIdx.x >> 4;
    const int oo = threadIdx.x & 15;
    const float* hr = sH[rr];
    float a0 = b2[oo], a1 = b2[oo + 16];
    #pragma unroll 8
    for (int j = 0; j < NHID; j += 4) {
        float4 h = *(const float4*)(hr + j);
        a0 = fmaf(h.x, W2[(j + 0) * 32 + oo], a0);
        a0 = fmaf(h.y, W2[(j + 1) * 32 + oo], a0);
        a0 = fmaf(h.z, W2[(j + 2) * 32 + oo], a0);
        a0 = fmaf(h.w, W2[(j + 3) * 32 + oo], a0);
        a1 = fmaf(h.x, W2[(j + 0) * 32 + oo + 16], a1);
        a1 = fmaf(h.y, W2[(j + 1) * 32 + oo + 16], a1);
        a1 = fmaf(h.z, W2[(j + 2) * 32 + oo + 16], a1);
        a1 = fmaf(h.w, W2[(j + 3) * 32 + oo + 16], a1);
    }
    const size_t ro = (size_t)(m0 + rr) * 64 + headoff;
    out[ro + oo]      = a0;
    out[ro + oo + 16] = a1;
}

__global__ __launch_bounds__(512, 1)
void gemm_fused(const __hip_bfloat16* __restrict__ Abi,
                const __hip_bfloat16* __restrict__ WbT,
                const float* __restrict__ bb1,
                const float* __restrict__ Wb2, const float* __restrict__ bb2,
                const __hip_bfloat16* __restrict__ Atri,
                const __hip_bfloat16* __restrict__ WtT,
                const float* __restrict__ bt1,
                const float* __restrict__ Wt2, const float* __restrict__ bt2,
                const float* __restrict__ inv,
                float* __restrict__ out)
{
    __shared__ float sH[32][HSTRIDE];
    // XCD-aware bijective swizzle: 256 blocks, 8 XCDs, 32 per XCD
    const int bid = (blockIdx.x & 7) * 32 + (blockIdx.x >> 3);
    if (bid < NROWS / 32) {
        head_body<KP_BI>(Abi, WbT, bb1, Wb2, bb2, inv, 0, 0,  out, bid * 32, sH);
    } else {
        head_body<NTRI>(Atri, WtT, bt1, Wt2, bt2, inv, 1, 32, out, (bid - NROWS / 32) * 32, sH);
    }
}

// ============ launcher ============
extern "C" void kernel_launch(void* const* d_in, const int* in_sizes, int n_in,
                              void* d_out, int out_size, void* d_ws, size_t ws_size,
                              hipStream_t stream) {
    const int*   src = (const int*)  d_in[0];
    const float* Wb1 = (const float*)d_in[1];
    const float* bb1 = (const float*)d_in[2];
    const float* Wb2 = (const float*)d_in[3];
    const float* bb2 = (const float*)d_in[4];
    const float* Wt1 = (const float*)d_in[5];
    const float* bt1 = (const float*)d_in[6];
    const float* Wt2 = (const float*)d_in[7];
    const float* bt2 = (const float*)d_in[8];
    float* outp = (float*)d_out;

    const int B = in_sizes[0] / TOK_S;           // 4096 rows

    char* ws = (char*)d_ws;
    __hip_bfloat16* Abi  = (__hip_bfloat16*)(ws);
    __hip_bfloat16* Atri = (__hip_bfloat16*)(ws + (size_t)B * KP_BI * 2);
    char* ws2 = ws + (size_t)B * KP_BI * 2 + (size_t)B * NTRI * 2;
    __hip_bfloat16* WbT  = (__hip_bfloat16*)(ws2);
    __hip_bfloat16* WtT  = (__hip_bfloat16*)(ws2 + (size_t)NHID * KP_BI * 2);
    float* inv = (float*)(ws2 + (size_t)NHID * KP_BI * 2 + (size_t)NHID * NTRI * 2);

    hist16<<<HBLKS, 256, 0, stream>>>(src, Wb1, Wt1, Abi, Atri, WbT, WtT, inv);

    gemm_fused<<<2 * (B / 32), 512, 0, stream>>>(
        Abi, WbT, bb1, Wb2, bb2, Atri, WtT, bt1, Wt2, bt2, inv, outp);
}

// Round 10
// 51.530 us; speedup vs baseline: 2.6293x; 1.2773x over previous
//
#include <hip/hip_runtime.h>
#include <hip/hip_bf16.h>

#define TOK_S    4096
#define NBI      1089      // 33*33
#define NBI_P    1092      // LDS pad (mult of 4)
#define KP_BI    1120      // A-matrix K padded to multiple of 32
#define NTRI     512
#define NTRI_P   544       // 512 real bins + 32 dump slots
#define NHID     256
#define NROWS    4096
#define HSTRIDE  (NHID + 4)

#define HIST_BLKS   (NROWS / 2)                       // 2048
#define TRANS_ELEMS (NHID * KP_BI + NHID * NTRI)      // 417792
#define TRANS_BLKS  (TRANS_ELEMS / 1024)              // 408 (exact)

typedef __attribute__((ext_vector_type(8))) short short8;   // 8 bf16
typedef __attribute__((ext_vector_type(4))) float f32x4;

static __device__ __forceinline__ unsigned int f2bf(float f) {
    __hip_bfloat16 h = __float2bfloat16(f);
    return (unsigned int)*reinterpret_cast<unsigned short*>(&h);
}

// ============ K1: histograms (2 rows/block, 8-tok groups, hoisted loads) ============
// DS-atomic rate-bound (~45 cyc / 64-lane RMW wave-instr, measured invariant
// across occupancy 9%-59% and 5 structural variants) -> ~38 us floor.
__global__ __launch_bounds__(256, 4)
void hist_trans(const int* __restrict__ src,
                const float* __restrict__ Wb1, const float* __restrict__ Wt1,
                __hip_bfloat16* __restrict__ Abi,
                __hip_bfloat16* __restrict__ Atri,
                __hip_bfloat16* __restrict__ WbT,
                __hip_bfloat16* __restrict__ WtT,
                float* __restrict__ inv)
{
    __shared__ int   s_bi [2][NBI_P];    // 8736 B
    __shared__ int   s_tri[2][NTRI_P];   // 4352 B
    __shared__ float s_ps [2][2][2];

    const int tid = threadIdx.x;

    // ---- transpose blocks (appended after hist blocks) ----
    if (blockIdx.x >= HIST_BLKS) {
        int base = (blockIdx.x - HIST_BLKS) * 1024 + tid;
        const int nb = NHID * KP_BI;
        #pragma unroll
        for (int i = 0; i < 4; ++i) {
            int idx = base + i * 256;
            if (idx < nb) {
                int c = idx / KP_BI, k = idx - c * KP_BI;
                WbT[idx] = __float2bfloat16(k < NBI ? Wb1[k * NHID + c] : 0.0f);
            } else {
                int j = idx - nb;
                int c = j >> 9, k = j & 511;
                WtT[j] = __float2bfloat16(Wt1[k * NHID + c]);
            }
        }
        return;
    }

    // ---- histogram blocks ----
    const int wave = tid >> 6;
    const int lane = tid & 63;
    const int wrow = wave >> 1;          // row within block (0/1)
    const int wpar = wave & 1;           // half of the row
    const size_t row = (size_t)blockIdx.x * 2 + wrow;
    const int dump = NTRI + (lane & 31);

    // vectorized zero
    for (int i = tid; i < 2 * NBI_P / 4;  i += 256) ((int4*)s_bi)[i]  = int4{0,0,0,0};
    for (int i = tid; i < 2 * NTRI_P / 4; i += 256) ((int4*)s_tri)[i] = int4{0,0,0,0};
    __syncthreads();

    int* bi  = s_bi[wrow];
    int* tri = s_tri[wrow];
    const int4* rowp = (const int4*)(src + row * TOK_S);
    const int*  rowt = src + row * TOK_S;

    // hoist ALL loads: 4 groups of 8 tokens (+2 overlap) per lane
    int4 A[4], Bv[4];
    int2 E[4];
    #pragma unroll
    for (int jj = 0; jj < 4; ++jj) {
        const int idx = wpar * 256 + jj * 64 + lane;   // group index in [0,512)
        A[jj]  = rowp[2 * idx];
        Bv[jj] = rowp[2 * idx + 1];
        if (idx != 511) E[jj] = *(const int2*)(rowt + 8 * idx + 8);  // 8B-aligned
        else            E[jj] = int2{0, 0};
    }

    #pragma unroll
    for (int jj = 0; jj < 4; ++jj) {
        const int t0 = A[jj].x, t1 = A[jj].y, t2 = A[jj].z, t3 = A[jj].w;
        const int t4 = Bv[jj].x, t5 = Bv[jj].y, t6 = Bv[jj].z, t7 = Bv[jj].w;
        const int t8 = E[jj].x, t9 = E[jj].y;
        const int b0 = t0 * 33 + t1;
        const int b1 = t1 * 33 + t2;
        const int b2 = t2 * 33 + t3;
        const int b3 = t3 * 33 + t4;
        const int b4 = t4 * 33 + t5;
        const int b5 = t5 * 33 + t6;
        const int b6 = t6 * 33 + t7;
        const int b7 = t7 * 33 + t8;
        atomicAdd(&bi[b0], 1);  atomicAdd(&bi[b1], 1);
        atomicAdd(&bi[b2], 1);  atomicAdd(&bi[b3], 1);
        atomicAdd(&bi[b4], 1);  atomicAdd(&bi[b5], 1);
        atomicAdd(&bi[b6], 1);  atomicAdd(&bi[b7], 1);
        const int u0 = (min(min(t0, t1), t2) > 0) ? ((b0 * 33 + t2) & 511) : dump;
        const int u1 = (min(min(t1, t2), t3) > 0) ? ((b1 * 33 + t3) & 511) : dump;
        const int u2 = (min(min(t2, t3), t4) > 0) ? ((b2 * 33 + t4) & 511) : dump;
        const int u3 = (min(min(t3, t4), t5) > 0) ? ((b3 * 33 + t5) & 511) : dump;
        const int u4 = (min(min(t4, t5), t6) > 0) ? ((b4 * 33 + t6) & 511) : dump;
        const int u5 = (min(min(t5, t6), t7) > 0) ? ((b5 * 33 + t7) & 511) : dump;
        const int u6 = (min(min(t6, t7), t8) > 0) ? ((b6 * 33 + t8) & 511) : dump;
        const int u7 = (min(min(t7, t8), t9) > 0) ? ((b7 * 33 + t9) & 511) : dump;
        atomicAdd(&tri[u0], 1); atomicAdd(&tri[u1], 1);
        atomicAdd(&tri[u2], 1); atomicAdd(&tri[u3], 1);
        atomicAdd(&tri[u4], 1); atomicAdd(&tri[u5], 1);
        atomicAdd(&tri[u6], 1); atomicAdd(&tri[u7], 1);
    }
    __syncthreads();

    // ---- export: int4 LDS reads, packed bf16 (uint2) global stores ----
    float bsum = 0.0f, tsum = 0.0f;
    __hip_bfloat16* arow = Abi + row * KP_BI;
    for (int g = wpar * 64 + lane; g < KP_BI / 4; g += 128) {   // 280 groups
        uint2 pk{0, 0};
        if (g < NBI_P / 4) {               // bins 4g..4g+3 readable
            int4 v = *(const int4*)&bi[4 * g];
            float f0, f1, f2, f3;
            int b = 4 * g;
            f0 = (b + 0 >= 33 && (b + 0) % 33 != 0 && b + 0 < NBI) ? (float)v.x : 0.0f;
            f1 = (b + 1 >= 33 && (b + 1) % 33 != 0 && b + 1 < NBI) ? (float)v.y : 0.0f;
            f2 = (b + 2 >= 33 && (b + 2) % 33 != 0 && b + 2 < NBI) ? (float)v.z : 0.0f;
            f3 = (b + 3 >= 33 && (b + 3) % 33 != 0 && b + 3 < NBI) ? (float)v.w : 0.0f;
            bsum += f0 + f1 + f2 + f3;
            pk.x = f2bf(f0) | (f2bf(f1) << 16);
            pk.y = f2bf(f2) | (f2bf(f3) << 16);
        }
        *(uint2*)(arow + 4 * g) = pk;
    }
    {
        const int g = wpar * 64 + lane;    // exactly 128 groups of 4
        int4 v = *(const int4*)&tri[4 * g];
        float f0 = (float)v.x, f1 = (float)v.y, f2 = (float)v.z, f3 = (float)v.w;
        tsum += f0 + f1 + f2 + f3;
        uint2 pk;
        pk.x = f2bf(f0) | (f2bf(f1) << 16);
        pk.y = f2bf(f2) | (f2bf(f3) << 16);
        *(uint2*)(Atri + row * NTRI + 4 * g) = pk;
    }
    #pragma unroll
    for (int s = 32; s; s >>= 1) {
        bsum += __shfl_xor(bsum, s, 64);
        tsum += __shfl_xor(tsum, s, 64);
    }
    if (lane == 0) { s_ps[wrow][wpar][0] = bsum; s_ps[wrow][wpar][1] = tsum; }
    __syncthreads();
    if (tid < 2) {
        float bs = s_ps[tid][0][0] + s_ps[tid][1][0];
        float ts = s_ps[tid][0][1] + s_ps[tid][1][1];
        size_t r2 = ((size_t)blockIdx.x * 2 + tid) * 2;
        inv[r2 + 0] = 1.0f / fmaxf(bs, 1.0f);
        inv[r2 + 1] = 1.0f / fmaxf(ts, 1.0f);
    }
}

// ============ K2: fused layer1 MFMA GEMM (BM=32, N=256) + relu/len + layer2 ============
template<int KP>
__device__ __forceinline__
void head_body(const __hip_bfloat16* __restrict__ A,
               const __hip_bfloat16* __restrict__ WT,
               const float* __restrict__ b1,
               const float* __restrict__ W2,
               const float* __restrict__ b2,
               const float* __restrict__ inv, const int invoff, const int headoff,
               float* __restrict__ out, const int m0,
               float (*sH)[HSTRIDE])
{
    const int wave = threadIdx.x >> 6;       // 8 waves
    const int lane = threadIdx.x & 63;
    const int wn   = wave * 32;
    const int fr   = lane & 15;
    const int kg   = lane >> 4;

    const __hip_bfloat16* A0 = A  + (size_t)(m0 + fr) * KP + kg * 8;
    const __hip_bfloat16* A1 = A0 + (size_t)16 * KP;
    const __hip_bfloat16* B0 = WT + (size_t)(wn + fr) * KP + kg * 8;
    const __hip_bfloat16* B1 = B0 + (size_t)16 * KP;

    f32x4 acc00 = {}, acc01 = {}, acc10 = {}, acc11 = {};
    #pragma unroll 4
    for (int k = 0; k < KP; k += 32) {
        short8 a0  = *(const short8*)(A0 + k);
        short8 a1  = *(const short8*)(A1 + k);
        short8 b0  = *(const short8*)(B0 + k);
        short8 b1v = *(const short8*)(B1 + k);
        acc00 = __builtin_amdgcn_mfma_f32_16x16x32_bf16(a0, b0,  acc00, 0, 0, 0);
        acc01 = __builtin_amdgcn_mfma_f32_16x16x32_bf16(a0, b1v, acc01, 0, 0, 0);
        acc10 = __builtin_amdgcn_mfma_f32_16x16x32_bf16(a1, b0,  acc10, 0, 0, 0);
        acc11 = __builtin_amdgcn_mfma_f32_16x16x32_bf16(a1, b1v, acc11, 0, 0, 0);
    }

    f32x4 accs[2][2] = { {acc00, acc01}, {acc10, acc11} };
    #pragma unroll
    for (int mf = 0; mf < 2; ++mf) {
        #pragma unroll
        for (int nf = 0; nf < 2; ++nf) {
            const int col = wn + nf * 16 + fr;
            const float bias = b1[col];
            #pragma unroll
            for (int r = 0; r < 4; ++r) {
                const int rl = mf * 16 + kg * 4 + r;
                const float iv = inv[(m0 + rl) * 2 + invoff];
                sH[rl][col] = fmaxf(fmaf(accs[mf][nf][r], iv, bias), 0.0f);
            }
        }
    }
    __syncthreads();

    const int r  = threadIdx.x >> 4;
    const int oo = threadIdx.x & 15;
    const float* hr = sH[r];
    float a0 = b2[oo], a1 = b2[oo + 16];
    #pragma unroll 8
    for (int j = 0; j < NHID; j += 4) {
        float4 h = *(const float4*)(hr + j);
        a0 = fmaf(h.x, W2[(j + 0) * 32 + oo], a0);
        a0 = fmaf(h.y, W2[(j + 1) * 32 + oo], a0);
        a0 = fmaf(h.z, W2[(j + 2) * 32 + oo], a0);
        a0 = fmaf(h.w, W2[(j + 3) * 32 + oo], a0);
        a1 = fmaf(h.x, W2[(j + 0) * 32 + oo + 16], a1);
        a1 = fmaf(h.y, W2[(j + 1) * 32 + oo + 16], a1);
        a1 = fmaf(h.z, W2[(j + 2) * 32 + oo + 16], a1);
        a1 = fmaf(h.w, W2[(j + 3) * 32 + oo + 16], a1);
    }
    const size_t ro = (size_t)(m0 + r) * 64 + headoff;
    out[ro + oo]      = a0;
    out[ro + oo + 16] = a1;
}

__global__ __launch_bounds__(512, 1)
void gemm_fused(const __hip_bfloat16* __restrict__ Abi,
                const __hip_bfloat16* __restrict__ WbT,
                const float* __restrict__ bb1,
                const float* __restrict__ Wb2, const float* __restrict__ bb2,
                const __hip_bfloat16* __restrict__ Atri,
                const __hip_bfloat16* __restrict__ WtT,
                const float* __restrict__ bt1,
                const float* __restrict__ Wt2, const float* __restrict__ bt2,
                const float* __restrict__ inv,
                float* __restrict__ out)
{
    __shared__ float sH[32][HSTRIDE];
    // XCD-aware bijective swizzle: 256 blocks, 8 XCDs, 32 per XCD
    const int bid = (blockIdx.x & 7) * 32 + (blockIdx.x >> 3);
    if (bid < NROWS / 32) {
        head_body<KP_BI>(Abi, WbT, bb1, Wb2, bb2, inv, 0, 0,  out, bid * 32, sH);
    } else {
        head_body<NTRI>(Atri, WtT, bt1, Wt2, bt2, inv, 1, 32, out, (bid - NROWS / 32) * 32, sH);
    }
}

// ============ launcher ============
extern "C" void kernel_launch(void* const* d_in, const int* in_sizes, int n_in,
                              void* d_out, int out_size, void* d_ws, size_t ws_size,
                              hipStream_t stream) {
    const int*   src = (const int*)  d_in[0];
    const float* Wb1 = (const float*)d_in[1];
    const float* bb1 = (const float*)d_in[2];
    const float* Wb2 = (const float*)d_in[3];
    const float* bb2 = (const float*)d_in[4];
    const float* Wt1 = (const float*)d_in[5];
    const float* bt1 = (const float*)d_in[6];
    const float* Wt2 = (const float*)d_in[7];
    const float* bt2 = (const float*)d_in[8];
    float* outp = (float*)d_out;

    const int B = in_sizes[0] / TOK_S;           // 4096 rows

    char* ws = (char*)d_ws;
    __hip_bfloat16* Abi  = (__hip_bfloat16*)(ws);
    __hip_bfloat16* Atri = (__hip_bfloat16*)(ws + (size_t)B * KP_BI * 2);
    char* ws2 = ws + (size_t)B * KP_BI * 2 + (size_t)B * NTRI * 2;
    __hip_bfloat16* WbT  = (__hip_bfloat16*)(ws2);
    __hip_bfloat16* WtT  = (__hip_bfloat16*)(ws2 + (size_t)NHID * KP_BI * 2);
    float* inv = (float*)(ws2 + (size_t)NHID * KP_BI * 2 + (size_t)NHID * NTRI * 2);

    hist_trans<<<HIST_BLKS + TRANS_BLKS, 256, 0, stream>>>(
        src, Wb1, Wt1, Abi, Atri, WbT, WtT, inv);

    gemm_fused<<<2 * (B / 32), 512, 0, stream>>>(
        Abi, WbT, bb1, Wb2, bb2, Atri, WtT, bt1, Wt2, bt2, inv, outp);
}